// Round 3
// baseline (300.233 us; speedup 1.0000x reference)
//
#include <hip/hip_runtime.h>
#include <hip/hip_bf16.h>

#define C_ 256
#define H_ 64
#define W_ 64
#define N_ 16
#define HW_ 4096
#define IMG_ (C_ * HW_)          // 1048576 elems (fp32 image)
#define PADIMG_ (66 * 66 * 256)  // 1115136 shorts per padded NHWC image
#define WT_ELEMS_ (9 * 16 * 256 * 16)

typedef short bf16x8 __attribute__((ext_vector_type(8)));
typedef float f32x16 __attribute__((ext_vector_type(16)));

__device__ __forceinline__ unsigned short f2bf(float f) {
  __hip_bfloat16 h = __float2bfloat16(f);  // RTNE
  return *reinterpret_cast<unsigned short*>(&h);
}

__device__ __forceinline__ void gld_lds16(const void* g, void* l) {
  __builtin_amdgcn_global_load_lds(
      (const __attribute__((address_space(1))) void*)g,
      (__attribute__((address_space(3))) void*)l, 16, 0, 0);
}

// ---------------------------------------------------------------------------
// Fused x->padded-NHWC-bf16 transform + mask logits (fp64, sign-exact).
// ---------------------------------------------------------------------------
__global__ __launch_bounds__(256) void xpadmask_kernel(
    const float* __restrict__ x, const float* __restrict__ wm,
    const float* __restrict__ bm, short* __restrict__ Xp,
    unsigned char* __restrict__ mask) {
  __shared__ unsigned short lds[64 * 260];
  __shared__ float wms[256];
  __shared__ double sums[4][64];
  const int h = blockIdx.x, img = blockIdx.y;
  const int tid = threadIdx.x;
  const int wv = tid >> 6, wl = tid & 63;
  wms[tid] = wm[tid];
  __syncthreads();
  const float* xi = x + (size_t)img * IMG_ + h * 64;
  double a0 = 0.0, a1 = 0.0, a2 = 0.0, a3 = 0.0;
#pragma unroll 4
  for (int i = 0; i < 16; ++i) {
#pragma unroll
    for (int u = 0; u < 4; ++u) {
      int c = (i * 4 + u) * 4 + wv;
      float v = xi[(size_t)c * HW_ + wl];
      lds[wl * 260 + c] = f2bf(v);
      double p = (double)v * (double)wms[c];
      if (u == 0) a0 += p;
      else if (u == 1) a1 += p;
      else if (u == 2) a2 += p;
      else a3 += p;
    }
  }
  sums[wv][wl] = (a0 + a1) + (a2 + a3);
  __syncthreads();
  short* Xpi = Xp + (size_t)img * PADIMG_ + ((h + 1) * 66 + 1) * 256;
#pragma unroll
  for (int j = 0; j < 16; ++j) {
    int w = j * 4 + wv;
    int c4 = wl * 4;
    uint2 d = *(const uint2*)&lds[w * 260 + c4];
    *(uint2*)&Xpi[(size_t)w * 256 + c4] = d;
  }
  if (wv == 0) {
    double t = sums[0][wl] + sums[1][wl] + sums[2][wl] + sums[3][wl] +
               (double)bm[0];
    mask[img * HW_ + h * 64 + wl] = (t > 0.0) ? 1 : 0;
  }
}

// ---------------------------------------------------------------------------
// Weight transform: Wt[t][kc][k][c16] = bf16(w[k][kc*16+c16][t])
// Layout so a conv wave's a-frag pair (64 lanes x 16B) is one contiguous,
// fully-coalesced 1KB global load.
// ---------------------------------------------------------------------------
__global__ __launch_bounds__(256) void wt_kernel(
    const float* __restrict__ w1, const float* __restrict__ w2,
    short* __restrict__ Wt1, short* __restrict__ Wt2) {
  const int k = blockIdx.x, c = threadIdx.x;
  const float* src = blockIdx.y ? w2 : w1;
  short* dst = blockIdx.y ? Wt2 : Wt1;
  const float* s = src + ((size_t)k * 256 + c) * 9;
  const int kc = c >> 4, ce = c & 15;
#pragma unroll
  for (int t = 0; t < 9; ++t)
    dst[(((size_t)t * 16 + kc) * 256 + k) * 16 + ce] = (short)f2bf(s[t]);
}

// ---------------------------------------------------------------------------
// Zero the padded halo (rows 0,65; cols 0,65) of Xp and Hp.
// ---------------------------------------------------------------------------
__global__ __launch_bounds__(128) void halo_zero(short* __restrict__ Xp,
                                                 short* __restrict__ Hp) {
  int p = blockIdx.x;  // 0..259 halo pixel id
  int r, c;
  if (p < 66) { r = 0; c = p; }
  else if (p < 132) { r = 65; c = p - 66; }
  else if (p < 196) { r = p - 131; c = 0; }
  else { r = p - 195; c = 65; }
  short* buf = blockIdx.z ? Hp : Xp;
  unsigned int* d = (unsigned int*)(buf + (size_t)blockIdx.y * PADIMG_ +
                                    (size_t)(r * 66 + c) * 256);
  d[threadIdx.x] = 0u;
}

// ---------------------------------------------------------------------------
// Implicit-GEMM 3x3 conv, v4 (deep prefetch: W 2-tap, B-frag 1-tap).
// Tile: 64 out-ch x 512 px (8 rows x 64 cols), 4 waves, 2 blocks/CU.
// MFMA 32x32x16 bf16, K-chunk = 16 in-ch (16 chunks), acc 2x4 f32x16.
// LDS 63360 B = 3 x 21120 B triple-buffered B tile only (W via L2->regs):
//   B[buf][khalf][660 slots][8ch x 2B]  -> conflict-free ds_read_b128.
// Per-tap pipeline (round-2 lesson: the tap body was latency-bound):
//   tap t: issue W(t+2) pair (2-tap ~190cyc lookahead for ~200cyc L2 lat),
//          ds_read b-frags for tap t+1 (1-tap lookahead for ~120cyc LDS lat),
//          8 MFMA on regs loaded >=1 tap ago (counted lgkm/vmcnt waits only).
// B stage (kk+2) issued at end of kk; vmcnt-FIFO retires it via the wait for
// W(kk+1,2) (issued tap 0 of kk+1) -> landed before end-of-kk+1 barrier ->
// safe to read after that barrier. Boundary = bare s_barrier, no drain.
// EPI 0: dstH[padded NHWC] = g ? relu(acc) : 0   (g = 3x3 OR of mask, fused
//        dilation -- dilate_kernel removed)
// EPI 1: dstF[NCHW fp32]   = xres + (g ? relu(acc):0)   (g = std mask)
// ---------------------------------------------------------------------------
#define BBUF 10560  // shorts per B k-chunk buffer (2 K-halves x 660 x 8)

__device__ __forceinline__ void stage_B(short* sm, int buf, const short* Xb,
                                        int ko, int wave, int lane) {
  short* Bd = sm + buf * BBUF;
  // 22 insts (11 per K-half; inst i<10 covers slots 64i..64i+63, inst 10
  // covers 596..659 overlapping inst 9 with identical data). Waves 2,3 dup
  // inst 21 (same bytes -> benign) so all waves issue 6 (vmcnt symmetric).
#pragma unroll
  for (int q = 0; q < 6; ++q) {
    int n = wave + 4 * q;
    if (n > 21) n = 21;
    const int h = (n >= 11) ? 1 : 0;
    const int i = n - h * 11;
    const int row0 = (i < 10) ? i * 64 : 596;
    gld_lds16(Xb + (size_t)(row0 + lane) * 256 + ko + h * 8,
              Bd + h * 5280 + row0 * 8);
  }
}

template <int EPI>
__global__ __launch_bounds__(256, 2) void conv_mfma(
    const short* __restrict__ src, const short* __restrict__ Wt,
    const unsigned char* __restrict__ gate, const float* __restrict__ xres,
    short* __restrict__ dstH, float* __restrict__ dstF, int swz) {
  __shared__ __align__(16) short sm[3 * BBUF];  // 63360 B -> 2 blocks/CU

  const int tid = threadIdx.x;
  const int lane = tid & 63, wave = tid >> 6;
  const int ln31 = lane & 31, kh = lane >> 5;

  // Block decode; swizzled path groups the 4 ch-sibling blocks on one XCD.
  int bx, by, bz;
  {
    int d = blockIdx.x + 4 * (blockIdx.y + 8 * blockIdx.z);
    if (swz) {
      int k = d & 7, j = d >> 3;
      bx = j & 3;
      by = (j >> 2) & 7;
      bz = ((j >> 5) << 3) + k;
    } else {
      bx = blockIdx.x;
      by = blockIdx.y;
      bz = blockIdx.z;
    }
  }
  const int ch0 = bx * 64;
  const int h0 = by * 8;
  const int img = bz;

  const short* Xb = src + (size_t)img * PADIMG_ + (size_t)(h0 * 66) * 256;
  // Per-lane W base: element ((t*16+kc)*256 + ch0 + khalf-interleaved lane)
  const short* WL = Wt + ((size_t)(ch0 + ln31)) * 16 + kh * 8;

  f32x16 acc[2][4];
#pragma unroll
  for (int i = 0; i < 2; ++i)
#pragma unroll
    for (int j = 0; j < 4; ++j)
#pragma unroll
      for (int e = 0; e < 16; ++e) acc[i][j][e] = 0.f;

  // Prologue: B(0), B(1) staged; W(0,t0) and W(0,t1) pairs issued.
  stage_B(sm, 0, Xb, 0, wave, lane);
  stage_B(sm, 1, Xb, 16, wave, lane);
  bf16x8 wc0 = *(const bf16x8*)(WL);                  // (t=0, kc=0)
  bf16x8 wc1 = *(const bf16x8*)(WL + 512);
  bf16x8 wn0 = *(const bf16x8*)(WL + 16 * 4096);      // (t=1, kc=0)
  bf16x8 wn1 = *(const bf16x8*)(WL + 16 * 4096 + 512);
  // vmcnt(4): both 12-load stages retired; the 4 W loads may stay in flight.
  asm volatile("s_waitcnt vmcnt(4)\n\ts_barrier" ::: "memory");

  int c0 = 0, c1 = 1, c2 = 2;
  for (int kk = 0; kk < 16; ++kk) {
    const short* Bth = sm + c0 * BBUF + kh * 5280 + (wave * 132 + ln31) * 8;
    bf16x8 bc[4], bn[4];
#pragma unroll
    for (int j = 0; j < 4; ++j)  // tap 0 frags (dy=0,dx=0)
      bc[j] = *(const bf16x8*)(Bth + ((j >> 1) * 66 + (j & 1) * 32) * 8);
#pragma unroll
    for (int t = 0; t < 9; ++t) {
      // W prefetch for tap t+2 (wraps into kk+1 taps 0,1; kk=15 tail loads
      // land in-bounds in Wt's kc=16 columns of taps 0/1, never consumed).
      const int nt = t + 2;
      const int ntkc = (nt < 9) ? (nt * 16 + kk) : ((nt - 9) * 16 + kk + 1);
      bf16x8 f0 = *(const bf16x8*)(WL + (size_t)ntkc * 4096);
      bf16x8 f1 = *(const bf16x8*)(WL + (size_t)ntkc * 4096 + 512);
      if (t < 8) {  // b-frag prefetch for tap t+1
        const int dy = (t + 1) / 3, dx = (t + 1) % 3;
#pragma unroll
        for (int j = 0; j < 4; ++j)
          bn[j] = *(const bf16x8*)(Bth +
                                   (((j >> 1) + dy) * 66 + (j & 1) * 32 + dx) * 8);
      }
      __builtin_amdgcn_s_setprio(1);
#pragma unroll
      for (int j = 0; j < 4; ++j) {
        acc[0][j] = __builtin_amdgcn_mfma_f32_32x32x16_bf16(wc0, bc[j],
                                                            acc[0][j], 0, 0, 0);
        acc[1][j] = __builtin_amdgcn_mfma_f32_32x32x16_bf16(wc1, bc[j],
                                                            acc[1][j], 0, 0, 0);
      }
      __builtin_amdgcn_s_setprio(0);
      wc0 = wn0; wc1 = wn1; wn0 = f0; wn1 = f1;
      if (t < 8) {
#pragma unroll
        for (int j = 0; j < 4; ++j) bc[j] = bn[j];
      }
    }
    // Next-next B stage after this kk's W issues (vmcnt-FIFO keeps it in
    // flight across the boundary; retired mid-compute of kk+1).
    if (kk < 14) stage_B(sm, c2, Xb, (kk + 2) * 16, wave, lane);
    if (kk < 15) asm volatile("s_barrier" ::: "memory");
    const int tmp = c0;
    c0 = c1;
    c1 = c2;
    c2 = tmp;
  }

  // Epilogue. 32x32 D layout: col(pixel)=lane&31, row(ch)=(reg&3)+8*(reg>>2)
  // +4*(lane>>5)  => reg group rg gives 4 consecutive channels.
  const int rb = h0 + wave * 2;
#pragma unroll
  for (int j = 0; j < 4; ++j) {
    const int r = rb + (j >> 1);
    const int col = (j & 1) * 32 + ln31;
    const int pidx = r * 64 + col;
    unsigned int g;
    if (EPI == 0) {
      // fused dilation: 3x3 OR of std mask around (r,col)
      g = 0;
#pragma unroll
      for (int dy = -1; dy <= 1; ++dy) {
        const int rr = r + dy;
        if (rr < 0 || rr >= H_) continue;
#pragma unroll
        for (int dx = -1; dx <= 1; ++dx) {
          const int cc = col + dx;
          if (cc < 0 || cc >= W_) continue;
          g |= gate[img * HW_ + rr * W_ + cc];
        }
      }
    } else {
      g = gate[img * HW_ + pidx];
    }
#pragma unroll
    for (int i = 0; i < 2; ++i) {
      const f32x16 v = acc[i][j];
#pragma unroll
      for (int rg = 0; rg < 4; ++rg) {
        const int ch = ch0 + i * 32 + rg * 8 + kh * 4;
        float e0 = g ? fmaxf(v[rg * 4 + 0], 0.f) : 0.f;
        float e1 = g ? fmaxf(v[rg * 4 + 1], 0.f) : 0.f;
        float e2 = g ? fmaxf(v[rg * 4 + 2], 0.f) : 0.f;
        float e3 = g ? fmaxf(v[rg * 4 + 3], 0.f) : 0.f;
        if (EPI == 0) {
          uint2 u;
          u.x = (unsigned int)f2bf(e0) | ((unsigned int)f2bf(e1) << 16);
          u.y = (unsigned int)f2bf(e2) | ((unsigned int)f2bf(e3) << 16);
          short* dp = dstH + (size_t)img * PADIMG_ +
                      ((size_t)((r + 1) * 66 + (col + 1))) * 256 + ch;
          *(uint2*)dp = u;
        } else {
          size_t o = (size_t)img * IMG_ + (size_t)ch * HW_ + pidx;
          dstF[o] = xres[o] + e0;
          dstF[o + HW_] = xres[o + HW_] + e1;
          dstF[o + 2 * HW_] = xres[o + 2 * HW_] + e2;
          dstF[o + 3 * HW_] = xres[o + 3 * HW_] + e3;
        }
      }
    }
  }
}

// ---------------------------------------------------------------------------
extern "C" void kernel_launch(void* const* d_in, const int* in_sizes, int n_in,
                              void* d_out, int out_size, void* d_ws,
                              size_t ws_size, hipStream_t stream) {
  const float* x = (const float*)d_in[0];
  const float* w1 = (const float*)d_in[1];
  const float* w2 = (const float*)d_in[2];
  const float* wmask = (const float*)d_in[3];
  const float* bmask = (const float*)d_in[4];
  float* out = (float*)d_out;

  char* ws = (char*)d_ws;
  unsigned char* mask = (unsigned char*)ws;  // 64 KB
  short* Wt1 = (short*)(ws + 65536);         // 1.125 MiB
  short* Wt2 = Wt1 + WT_ELEMS_;              // 1.125 MiB
  const size_t fixed = 65536 + 4 * (size_t)WT_ELEMS_;  // mask + 2 Wt (bytes)
  short* Xp = (short*)(ws + fixed);

  const size_t tailpad = 32768;  // safety pad past last image
  const size_t per_img = 2 * (size_t)PADIMG_ * 2;  // Xp + Hp bytes per image
  int B = (ws_size > fixed + tailpad)
              ? (int)((ws_size - fixed - tailpad) / per_img) : 0;
  if (B > N_) B = N_;
  if (B < 1) B = 1;
  short* Hp = Xp + (size_t)B * PADIMG_;

  wt_kernel<<<dim3(256, 2), 256, 0, stream>>>(w1, w2, Wt1, Wt2);
  halo_zero<<<dim3(260, B, 2), 128, 0, stream>>>(Xp, Hp);

  for (int n0 = 0; n0 < N_; n0 += B) {
    const int nb = (N_ - n0 < B) ? (N_ - n0) : B;
    const int swz = (nb % 8 == 0) ? 1 : 0;
    xpadmask_kernel<<<dim3(64, nb), 256, 0, stream>>>(
        x + (size_t)n0 * IMG_, wmask, bmask, Xp, mask + n0 * HW_);
    conv_mfma<0><<<dim3(4, 8, nb), 256, 0, stream>>>(
        Xp, Wt1, mask + n0 * HW_, nullptr, Hp, nullptr, swz);
    conv_mfma<1><<<dim3(4, 8, nb), 256, 0, stream>>>(
        Hp, Wt2, mask + n0 * HW_, x + (size_t)n0 * IMG_, nullptr,
        out + (size_t)n0 * IMG_, swz);
  }
}